// Round 1
// baseline (455.901 us; speedup 1.0000x reference)
//
#include <hip/hip_runtime.h>

#define NBATCH 4
#define NPTS   16384
#define NQ     4096
#define NCH    64
#define K      32
#define CHOUT  67   // 3 + NCH

// ---------------------------------------------------------------------------
// Kernel 1: brute-force exact top-32 KNN + centered-xyz channels.
// block = 256 (4 waves); each wave owns QPW=4 queries; block stages xyz tiles
// into LDS. Top-32 list is distributed across lanes 0..31 (lane e holds entry
// e of the sorted-by-(dist,idx) list). Distances use __f*_rn intrinsics so
// rounding matches the numpy/jax fp32 reference exactly (no fma contraction).
// ---------------------------------------------------------------------------
constexpr int TILE = 2048;   // points per LDS tile (24 KB AoS)
constexpr int QPW  = 4;      // queries per wave
constexpr int QPB  = 16;     // queries per block (4 waves * 4)

__global__ __launch_bounds__(256) void knn_kernel(
    const float* __restrict__ xyz,
    const float* __restrict__ new_xyz,
    int*   __restrict__ out_idx,
    float* __restrict__ out)
{
    __shared__ __align__(16) float pts[TILE * 3];

    const int tid  = threadIdx.x;
    const int lane = tid & 63;
    const int wave = tid >> 6;
    const int b    = blockIdx.x >> 8;                  // 256 blocks per batch
    const int q0   = (blockIdx.x & 255) * QPB + wave * QPW;

    const float* xb = xyz + (size_t)b * NPTS * 3;

    // Query coords: wave-uniform -> force into SGPRs.
    float qx[QPW], qy[QPW], qz[QPW];
#pragma unroll
    for (int j = 0; j < QPW; ++j) {
        const int base = ((b * NQ) + q0 + j) * 3;
        qx[j] = __int_as_float(__builtin_amdgcn_readfirstlane(__float_as_int(new_xyz[base + 0])));
        qy[j] = __int_as_float(__builtin_amdgcn_readfirstlane(__float_as_int(new_xyz[base + 1])));
        qz[j] = __int_as_float(__builtin_amdgcn_readfirstlane(__float_as_int(new_xyz[base + 2])));
    }

    float ld[QPW]; int li[QPW]; float T[QPW];
#pragma unroll
    for (int j = 0; j < QPW; ++j) {
        ld[j] = __int_as_float(0x7f800000);   // +inf
        li[j] = 0x7fffffff;
        T[j]  = __int_as_float(0x7f800000);
    }

    for (int t0 = 0; t0 < NPTS; t0 += TILE) {
        __syncthreads();
        {   // stage tile (AoS, float4 chunks; 24 KB is 16B-aligned multiples)
            const float4* src = (const float4*)(xb + (size_t)t0 * 3);
            float4* dst = (float4*)pts;
            for (int k2 = tid; k2 < TILE * 3 / 4; k2 += 256) dst[k2] = src[k2];
        }
        __syncthreads();

        for (int i = lane; i < TILE; i += 64) {
            const float px = pts[i * 3 + 0];
            const float py = pts[i * 3 + 1];
            const float pz = pts[i * 3 + 2];
            const int cand = t0 + i;
#pragma unroll
            for (int j = 0; j < QPW; ++j) {
                // EXACT reference rounding: ((dx^2 + dy^2) + dz^2), rn, no fma.
                const float dx = __fsub_rn(qx[j], px);
                const float dy = __fsub_rn(qy[j], py);
                const float dz = __fsub_rn(qz[j], pz);
                const float d  = __fadd_rn(__fadd_rn(__fmul_rn(dx, dx), __fmul_rn(dy, dy)),
                                           __fmul_rn(dz, dz));
                unsigned long long m = __ballot(d < T[j]);
                while (m) {
                    const int c = __ffsll(m) - 1;   // ascending lane = ascending index
                    m &= m - 1;
                    const float dn  = __int_as_float(__builtin_amdgcn_readlane(__float_as_int(d), c));
                    const int   inw = __builtin_amdgcn_readlane(cand, c);
                    if (dn < T[j]) {                // re-check vs freshest threshold
                        // entries strictly greater shift right; equal-d entries
                        // (smaller idx, inserted earlier) stay put -> tie order ok
                        unsigned long long sh = __ballot(ld[j] > dn) & 0xffffffffull;
                        const int p = __ffsll(sh) - 1;       // insert position
                        const float pd = __shfl_up(ld[j], 1);
                        const int   pi = __shfl_up(li[j], 1);
                        if ((sh >> lane) & 1) { ld[j] = pd; li[j] = pi; }
                        if (lane == p)        { ld[j] = dn; li[j] = inw; }
                        T[j] = __int_as_float(__builtin_amdgcn_readlane(__float_as_int(ld[j]), 31));
                    }
                }
            }
        }
    }

    // Epilogue: write idx + centered xyz channels (0..2).
#pragma unroll
    for (int j = 0; j < QPW; ++j) {
        if (lane < K) {
            const int q   = q0 + j;
            const int idx = li[j];
            out_idx[((size_t)(b * NQ) + q) * K + lane] = idx;
            const float px = xb[idx * 3 + 0];
            const float py = xb[idx * 3 + 1];
            const float pz = xb[idx * 3 + 2];
            const size_t plane = (size_t)NQ * K;
            const size_t o = (((size_t)b * CHOUT + 0) * NQ + q) * K + lane;
            out[o]             = __fsub_rn(px, qx[j]);
            out[o + plane]     = __fsub_rn(py, qy[j]);
            out[o + 2 * plane] = __fsub_rn(pz, qz[j]);
        }
    }
}

// ---------------------------------------------------------------------------
// Kernel 2: feature gather, channels 3..66.
// grid = B(4) x qtiles(8 of 512 queries) x cgroups(16 of 4 channels) = 512.
// Per channel: stage the 64 KB feature row in LDS, gather with LDS reads,
// coalesced stores. idx re-read from L2 per channel (2 MB array, cheap).
// ---------------------------------------------------------------------------
__global__ __launch_bounds__(256) void gather_kernel(
    const float* __restrict__ features,
    const int*   __restrict__ idx,
    float* __restrict__ out)
{
    __shared__ __align__(16) float row[NPTS];   // 64 KB

    const int tid = threadIdx.x;
    const int bid = blockIdx.x;
    const int cg  = bid & 15;
    const int qt  = (bid >> 4) & 7;
    const int b   = bid >> 7;
    const int qbase = qt * 512;

    const int* gidx = idx + ((size_t)b * NQ + qbase) * K;

#pragma unroll 1
    for (int ci = 0; ci < 4; ++ci) {
        const int c = cg * 4 + ci;
        const float* src = features + ((size_t)b * NCH + c) * NPTS;
        __syncthreads();   // protect previous channel's reads before restage
        for (int k2 = tid; k2 < NPTS / 4; k2 += 256)
            ((float4*)row)[k2] = ((const float4*)src)[k2];
        __syncthreads();
        float* dst = out + (((size_t)b * CHOUT + 3 + c) * NQ + qbase) * K;
        for (int p = tid; p < 512 * K; p += 256) {
            dst[p] = row[gidx[p]];
        }
    }
}

extern "C" void kernel_launch(void* const* d_in, const int* in_sizes, int n_in,
                              void* d_out, int out_size, void* d_ws, size_t ws_size,
                              hipStream_t stream) {
    const float* xyz      = (const float*)d_in[0];
    const float* new_xyz  = (const float*)d_in[1];
    const float* features = (const float*)d_in[2];
    // d_in[3] = nsample scalar (always 32) — compile-time constant here.
    float* out    = (float*)d_out;
    int*   ws_idx = (int*)d_ws;   // 4*4096*32*4 = 2 MB scratch

    knn_kernel<<<dim3(NBATCH * (NQ / QPB)), dim3(256), 0, stream>>>(xyz, new_xyz, ws_idx, out);
    gather_kernel<<<dim3(512), dim3(256), 0, stream>>>(features, ws_idx, out);
}